// Round 1
// baseline (998.044 us; speedup 1.0000x reference)
//
#include <hip/hip_runtime.h>

// ConvQuad2D: out[b,h,w,o] = bias[o]
//   + sum_{i,c} p[i,c] * Klin[i,c,o]                     (5x5 SAME conv)
//   + sum_{d,i,j} p[i,d] * p[j,d] * Wq[d,i,j,o]          (Volterra quadratic)
// where p[i,c] = x[b, h+ih-2, w+iw-2, c], i = ih*5+iw (zero pad).
//
// Strategy (round 1, fp32 correctness baseline):
//  - thread = pixel; acc[16] in VGPRs (o-amortized: one pair product feeds 16 FMAs)
//  - two-stage contraction per (d, i):  s[o] = Klin[i,d,o] + sum_j p[j,d]*Wq[d,i,j,o]
//                                       acc[o] += p[i,d] * s[o]
//    (linear conv folded into the s-init for free)
//  - per-channel weight slice Wq[d] (40 KB) staged in LDS each d-phase; all
//    inner-loop weight reads are wave-uniform -> LDS broadcast, conflict-free
//  - patch pc[4][25] fully statically indexed (d,j unrolled) -> stays in VGPRs;
//    the dynamically-indexed p[i,d] is re-read from global x (L1-hot)

#define BH 8
#define HH 250
#define WW 250
#define NPIX (BH * HH * WW)

__device__ __forceinline__ void fma4(float p, const float4& w, float4& s) {
    s.x = fmaf(p, w.x, s.x);
    s.y = fmaf(p, w.y, s.y);
    s.z = fmaf(p, w.z, s.z);
    s.w = fmaf(p, w.w, s.w);
}

__global__ __launch_bounds__(256) void convquad_kernel(
    const float* __restrict__ x,       // (8,250,250,4)
    const float* __restrict__ lin_w,   // (5,5,4,16)
    const float* __restrict__ quad_w,  // (4,25,25,16)
    const float* __restrict__ bias,    // (16,)
    float* __restrict__ out)           // (8,250,250,16)
{
    __shared__ float sW[25 * 25 * 16];  // 40 KB: quad weights, current channel d
    __shared__ float sL[25 * 16];       // 1.6 KB: linear weights, current channel d

    const int pix = blockIdx.x * 256 + threadIdx.x;
    const bool valid = pix < NPIX;
    int w = 0, h = 0, b = 0;
    if (valid) {
        w = pix % WW;
        int t = pix / WW;
        h = t % HH;
        b = t / HH;
    }

    // ---- load 5x5x4 patch into registers, statically indexed ----
    float pc[4][25];
    {
        const float4* xg = (const float4*)x;  // C=4 -> one float4 per (b,h,w)
        #pragma unroll
        for (int kh = 0; kh < 5; ++kh) {
            int r = h + kh - 2;
            #pragma unroll
            for (int kw = 0; kw < 5; ++kw) {
                int c = w + kw - 2;
                float4 v = make_float4(0.f, 0.f, 0.f, 0.f);
                if (valid && (unsigned)r < (unsigned)HH && (unsigned)c < (unsigned)WW)
                    v = xg[(b * HH + r) * WW + c];
                const int i = kh * 5 + kw;
                pc[0][i] = v.x; pc[1][i] = v.y; pc[2][i] = v.z; pc[3][i] = v.w;
            }
        }
    }

    // ---- init accumulator with bias ----
    float4 a0, a1, a2, a3;
    {
        const float4* b4 = (const float4*)bias;
        a0 = b4[0]; a1 = b4[1]; a2 = b4[2]; a3 = b4[3];
    }

    // ---- 4 channel phases ----
    #pragma unroll
    for (int d = 0; d < 4; ++d) {
        // stage Wq[d] (2500 float4) and Klin[:, d, :] (100 float4) into LDS
        {
            const float4* q4 = (const float4*)(quad_w + d * 25 * 25 * 16);
            float4* s4 = (float4*)sW;
            for (int t = threadIdx.x; t < 2500; t += 256) s4[t] = q4[t];
            float4* l4 = (float4*)sL;
            const float4* k4 = (const float4*)lin_w;
            for (int t = threadIdx.x; t < 100; t += 256) {
                int i = t >> 2, o4 = t & 3;
                l4[t] = k4[(i * 4 + d) * 4 + o4];
            }
        }
        __syncthreads();

        #pragma unroll 1
        for (int i = 0; i < 25; ++i) {
            // p[i,d] with zero padding (dynamic i -> re-read from global, L1-hot)
            int ih = (i * 13) >> 6;   // i/5 for i in [0,25)
            int iw = i - ih * 5;
            int r = h + ih - 2, c = w + iw - 2;
            float pi = 0.f;
            if (valid && (unsigned)r < (unsigned)HH && (unsigned)c < (unsigned)WW)
                pi = x[((b * HH + r) * WW + c) * 4 + d];

            const float4* wrow = (const float4*)(sW + i * 25 * 16);
            const float4* lrow = (const float4*)(sL + i * 16);
            float4 s0 = lrow[0], s1 = lrow[1], s2 = lrow[2], s3 = lrow[3];
            #pragma unroll
            for (int j = 0; j < 25; ++j) {
                const float pj = pc[d][j];
                fma4(pj, wrow[j * 4 + 0], s0);
                fma4(pj, wrow[j * 4 + 1], s1);
                fma4(pj, wrow[j * 4 + 2], s2);
                fma4(pj, wrow[j * 4 + 3], s3);
            }
            fma4(pi, s0, a0);
            fma4(pi, s1, a1);
            fma4(pi, s2, a2);
            fma4(pi, s3, a3);
        }
        __syncthreads();
    }

    if (valid) {
        float4* og = (float4*)out;
        og[pix * 4 + 0] = a0;
        og[pix * 4 + 1] = a1;
        og[pix * 4 + 2] = a2;
        og[pix * 4 + 3] = a3;
    }
}

extern "C" void kernel_launch(void* const* d_in, const int* in_sizes, int n_in,
                              void* d_out, int out_size, void* d_ws, size_t ws_size,
                              hipStream_t stream) {
    const float* x      = (const float*)d_in[0];
    const float* lin_w  = (const float*)d_in[1];
    const float* quad_w = (const float*)d_in[2];
    const float* bias   = (const float*)d_in[3];
    float* out = (float*)d_out;

    dim3 grid((NPIX + 255) / 256);
    convquad_kernel<<<grid, dim3(256), 0, stream>>>(x, lin_w, quad_w, bias, out);
}

// Round 2
// 299.279 us; speedup vs baseline: 3.3348x; 3.3348x over previous
//
#include <hip/hip_runtime.h>

// ConvQuad2D via MFMA (f16 inputs, fp32 accumulate):
//   per channel d:  S_i[pix,o] = sum_j p[pix,j,d] * B[d,i,j,o]      (MFMA 16x16x32_f16)
//                   acc[pix,o] += p[pix,i,d] * S_i[pix,o]           (VALU stage-2)
// with the j=25 "constant 1" column carrying the linear conv:
//   p[pix,25,d]=1, B[d,i,25,o]=Klin[i,d,o]  => stage-2 adds sum_i p_i*Klin[i,d,o].
// bias folded into acc init. Round-1 post-mortem: old kernel was LDS-issue bound
// (10,400 broadcast ds_read_b128/wave @ ~8cyc = measured 1055us). Here weights are
// fetched as pre-transposed MFMA B-fragments from global (L1-hot dwordx4), LDS holds
// only small wave-private patch buffers -> no __syncthreads at all.
//
// MFMA layouts (gfx950, HW-verified per guide):
//   A[m][k]: m=lane&15, k=(lane>>4)*8+e  (half8, e ascending)
//   B[k][n]: n=lane&15, k=(lane>>4)*8+e
//   C/D:     col=lane&15, row=(lane>>4)*4+reg

typedef _Float16 half8 __attribute__((ext_vector_type(8)));
typedef _Float16 half4 __attribute__((ext_vector_type(4)));
typedef float floatx4 __attribute__((ext_vector_type(4)));

#define BB 8
#define HH 250
#define WW 250
#define NPIX (BB * HH * WW)   // 500,000
#define NF 16
#define NI 25                  // patch positions

// ---------- pre-pass: build B fragments in MFMA lane order ----------
// fragB layout: [d*25+i][lane][e]  (f16), 100*64*8 = 51,200 half = 102,400 B
__global__ void prep_frags(const float* __restrict__ lin_w,   // (5,5,4,16)
                           const float* __restrict__ quad_w,  // (4,25,25,16)
                           _Float16* __restrict__ fragB) {
    const int di = blockIdx.x;        // 0..99
    const int lane = threadIdx.x;     // 0..63
    const int d = di / 25, i = di % 25;
    const int n = lane & 15;
    const int kbase = (lane >> 4) * 8;
    half8 f;
    #pragma unroll
    for (int e = 0; e < 8; ++e) {
        const int k = kbase + e;
        float v = 0.f;
        if (k < 25)       v = quad_w[((d * 25 + i) * 25 + k) * 16 + n];
        else if (k == 25) v = lin_w[(i * 4 + d) * 16 + n];
        f[e] = (_Float16)v;
    }
    *(half8*)(fragB + (di * 64 + lane) * 8) = f;
}

// ---------- main kernel: 64 pixels per wave, 4 waves per block ----------
__global__ __launch_bounds__(256) void convquad_mfma(
    const float* __restrict__ x,       // (8,250,250,4)
    const float* __restrict__ bias,    // (16,)
    const _Float16* __restrict__ fragB,
    float* __restrict__ out)           // (8,250,250,16)
{
    // wave-private LDS (no cross-wave sharing -> no __syncthreads)
    __shared__ _Float16 sA[4][64][40];   // [wave][pix][k] pad 32->40 (bank spread)
    __shared__ _Float16 sP[4][26][64];   // [wave][j][pix]  (stage-2 reads)

    const int wave = threadIdx.x >> 6;
    const int lane = threadIdx.x & 63;
    const int m = lane & 15;            // MFMA row/col within 16
    const int q = lane >> 4;            // quad 0..3
    const int pixbase = blockIdx.x * 256 + wave * 64;

    const int pix = pixbase + lane;
    const int pixc = min(pix, NPIX - 1);

    const int w  = pixc % WW;
    const int t1 = pixc / WW;
    const int h  = t1 % HH;
    const int b  = t1 / HH;

    // clamped row/col bases + validity factors (zero padding via multiply)
    int   rowb4[5], cof4[5];
    float rmsk[5], cmsk[5];
    #pragma unroll
    for (int k5 = 0; k5 < 5; ++k5) {
        int r = h + k5 - 2;
        rmsk[k5] = (r >= 0 && r < HH) ? 1.f : 0.f;
        int rc = min(max(r, 0), HH - 1);
        rowb4[k5] = ((b * HH + rc) * WW) * 4;
        int c = w + k5 - 2;
        cmsk[k5] = (c >= 0 && c < WW) ? 1.f : 0.f;
        int cc = min(max(c, 0), WW - 1);
        cof4[k5] = cc * 4;
    }

    // accumulators: acc[t][r] for pix = pixbase + t*16 + q*4 + r, o = m
    const float bo = bias[m];
    floatx4 acc[4];
    #pragma unroll
    for (int t = 0; t < 4; ++t) acc[t] = (floatx4){bo, bo, bo, bo};

    _Float16* sAw = &sA[wave][0][0];
    _Float16* sPw = &sP[wave][0][0];

    #pragma unroll 1
    for (int d = 0; d < 4; ++d) {
        // ---- im2col for this channel: own pixel (=lane) ----
        half8 grp[4];
        #pragma unroll
        for (int g = 0; g < 4; ++g) grp[g] = (half8)(_Float16)0.f;
        #pragma unroll
        for (int kh = 0; kh < 5; ++kh) {
            #pragma unroll
            for (int kw = 0; kw < 5; ++kw) {
                const int j = kh * 5 + kw;
                float v = x[rowb4[kh] + cof4[kw] + d] * (rmsk[kh] * cmsk[kw]);
                _Float16 hv = (_Float16)v;
                sPw[j * 64 + lane] = hv;        // [j][pix] for stage-2
                grp[j >> 3][j & 7] = hv;        // pack own pix's k-groups
            }
        }
        sPw[25 * 64 + lane] = (_Float16)1.f;    // constant-1 column (linear term)
        grp[3][1] = (_Float16)1.f;              // k=25

        // ---- A buffer: [pix][k0..31] contiguous, then read MFMA A-frags ----
        #pragma unroll
        for (int g = 0; g < 4; ++g)
            *(half8*)(sAw + lane * 40 + g * 8) = grp[g];
        half8 af[4];
        #pragma unroll
        for (int t = 0; t < 4; ++t)
            af[t] = *(half8*)(sAw + (t * 16 + m) * 40 + q * 8);

        // ---- i loop: MFMA + stage-2 ----
        const _Float16* fb = fragB + (d * 25 * 64 + lane) * 8;
        #pragma unroll
        for (int i = 0; i < NI; ++i) {
            const half8 bf = *(const half8*)(fb + i * 64 * 8);
            #pragma unroll
            for (int t = 0; t < 4; ++t) {
                floatx4 S = __builtin_amdgcn_mfma_f32_16x16x32_f16(
                    af[t], bf, (floatx4){0.f, 0.f, 0.f, 0.f}, 0, 0, 0);
                const half4 p4 = *(half4*)(sPw + i * 64 + t * 16 + q * 4);
                acc[t][0] += (float)p4[0] * S[0];
                acc[t][1] += (float)p4[1] * S[1];
                acc[t][2] += (float)p4[2] * S[2];
                acc[t][3] += (float)p4[3] * S[3];
            }
        }
    }

    // ---- store: lane holds (pix = pixbase + t*16 + q*4 + r, o = m) ----
    #pragma unroll
    for (int t = 0; t < 4; ++t) {
        #pragma unroll
        for (int r = 0; r < 4; ++r) {
            const int pg = pixbase + t * 16 + q * 4 + r;
            if (pg < NPIX) out[pg * NF + m] = acc[t][r];
        }
    }
}

extern "C" void kernel_launch(void* const* d_in, const int* in_sizes, int n_in,
                              void* d_out, int out_size, void* d_ws, size_t ws_size,
                              hipStream_t stream) {
    const float* x      = (const float*)d_in[0];
    const float* lin_w  = (const float*)d_in[1];
    const float* quad_w = (const float*)d_in[2];
    const float* bias   = (const float*)d_in[3];
    float* out = (float*)d_out;
    _Float16* fragB = (_Float16*)d_ws;   // 102,400 B

    prep_frags<<<dim3(100), dim3(64), 0, stream>>>(lin_w, quad_w, fragB);

    const int nblocks = (NPIX + 255) / 256;   // 1954, 64 pix per wave
    convquad_mfma<<<dim3(nblocks), dim3(256), 0, stream>>>(x, bias, fragB, out);
}